// Round 5
// baseline (141.707 us; speedup 1.0000x reference)
//
#include <hip/hip_runtime.h>
#include <cstddef>

#define B_     4
#define NTOK   1024
#define DMODEL 768
#define NH     12
#define IMGC   256
#define NPIX   1024

typedef __attribute__((ext_vector_type(8))) short bf16x8;
typedef __attribute__((ext_vector_type(4))) float f32x4;
typedef __attribute__((ext_vector_type(8))) unsigned short u16x8;

static __device__ __forceinline__ unsigned short f2bf(float f) {
  unsigned int u = __float_as_uint(f);
  u += 0x7FFFu + ((u >> 16) & 1u);
  return (unsigned short)(u >> 16);
}

// swizzled LDS byte address: 128B rows, XOR bits 4..6 with row&7
#define SWZ(row, b) (((row) << 7) + ((b) ^ (((row) & 7) << 4)))

#define GLOAD16(g, l) __builtin_amdgcn_global_load_lds(                      \
    (const __attribute__((address_space(1))) void*)(g),                      \
    (__attribute__((address_space(3))) void*)(l), 16, 0, 0)

// stage a 128-row x 64-col bf16 panel pair via global_load_lds (pre-swizzled src)
static __device__ __forceinline__ void stage_pair(const unsigned short* A0, int lda,
                                                  const unsigned short* B0, int ldb,
                                                  char* as, char* bs,
                                                  int w, int l, int rsel, int slotp) {
#pragma unroll
  for (int i = 0; i < 4; i++) {
    const int chunk = (i << 2) + w;
    const int row = (chunk << 3) + rsel;
    GLOAD16(A0 + (size_t)row * lda + (slotp << 3), as + (chunk << 10) + (l << 4));
    GLOAD16(B0 + (size_t)row * ldb + (slotp << 3), bs + (chunk << 10) + (l << 4));
  }
}

// ---------------- K0: merged converts + BN-accumulator zeroing
__global__ __launch_bounds__(256) void k_cvt(const float* __restrict__ X,
                                             const float* __restrict__ Wqkv,
                                             const float* __restrict__ W2,
                                             unsigned short* __restrict__ Xb,
                                             unsigned short* __restrict__ Wtb,
                                             unsigned short* __restrict__ W2b,
                                             float* __restrict__ bnacc) {
  __shared__ unsigned short T[32][33];
  const int bid = blockIdx.x;
  const int t = threadIdx.x;
  if (bid < 1536) {
    const size_t i8 = (size_t)bid * 256 + t;
    const float4 a = *(const float4*)(X + i8 * 8);
    const float4 b = *(const float4*)(X + i8 * 8 + 4);
    u16x8 o;
    o[0] = f2bf(a.x); o[1] = f2bf(a.y); o[2] = f2bf(a.z); o[3] = f2bf(a.w);
    o[4] = f2bf(b.x); o[5] = f2bf(b.y); o[6] = f2bf(b.z); o[7] = f2bf(b.w);
    *(u16x8*)(Xb + i8 * 8) = o;
  } else if (bid < 3264) {
    const int b2 = bid - 1536;
    const int n0 = (b2 % 72) * 32, k0 = (b2 / 72) * 32;
    const int tx = t & 31, ty = t >> 5;
#pragma unroll
    for (int i = 0; i < 4; i++) {
      int kl = ty + i * 8;
      T[tx][kl] = f2bf(Wqkv[(size_t)(k0 + kl) * 2304 + n0 + tx]);
    }
    __syncthreads();
#pragma unroll
    for (int i = 0; i < 4; i++) {
      int nl = ty + i * 8;
      Wtb[(size_t)(n0 + nl) * 768 + k0 + tx] = T[nl][tx];
    }
  } else if (bid < 3360) {
    const size_t i8 = (size_t)(bid - 3264) * 256 + t;
    const float4 a = *(const float4*)(W2 + i8 * 8);
    const float4 b = *(const float4*)(W2 + i8 * 8 + 4);
    u16x8 o;
    o[0] = f2bf(a.x); o[1] = f2bf(a.y); o[2] = f2bf(a.z); o[3] = f2bf(a.w);
    o[4] = f2bf(b.x); o[5] = f2bf(b.y); o[6] = f2bf(b.z); o[7] = f2bf(b.w);
    *(u16x8*)(W2b + i8 * 8) = o;
  } else {
    for (int i = t; i < 1536; i += 256) bnacc[i] = 0.0f;
  }
}

// ---------------- K1: QKV GEMM bf16 MFMA, 2-phase prefetch double-buffer
__global__ __launch_bounds__(256) void k_qkv_gemm(const unsigned short* __restrict__ Xb,
                                                  const unsigned short* __restrict__ Wt,
                                                  unsigned short* __restrict__ q,
                                                  unsigned short* __restrict__ k,
                                                  unsigned short* __restrict__ v) {
  __shared__ __align__(16) char AsB[2][16384];
  __shared__ __align__(16) char BsB[2][16384];
  const int t = threadIdx.x;
  const int w = t >> 6, l = t & 63;
  const int r = l & 15, g = l >> 4;
  const int wr = w >> 1, wc = w & 1;
  const int m0 = blockIdx.y * 128;
  const int n0 = blockIdx.x * 128;
  const int rsel  = l >> 3;
  const int slotp = (l & 7) ^ (rsel & 7);
  const unsigned short* A0 = Xb + (size_t)m0 * 768;
  const unsigned short* B0 = Wt + (size_t)n0 * 768;
  f32x4 acc[4][4] = {};

  stage_pair(A0, 768, B0, 768, AsB[0], BsB[0], w, l, rsel, slotp);
  __syncthreads();

  for (int step = 0; step < 12; ++step) {
    const int cur = step & 1;
    if (step < 11)
      stage_pair(A0 + (step + 1) * 64, 768, B0 + (step + 1) * 64, 768,
                 AsB[cur ^ 1], BsB[cur ^ 1], w, l, rsel, slotp);
#pragma unroll
    for (int kk = 0; kk < 2; kk++) {
      bf16x8 a[4], b[4];
#pragma unroll
      for (int m = 0; m < 4; m++) {
        const int row = wr * 64 + m * 16 + r;
        a[m] = *(const bf16x8*)(AsB[cur] + SWZ(row, kk * 64 + (g << 4)));
      }
#pragma unroll
      for (int n = 0; n < 4; n++) {
        const int row = wc * 64 + n * 16 + r;
        b[n] = *(const bf16x8*)(BsB[cur] + SWZ(row, kk * 64 + (g << 4)));
      }
#pragma unroll
      for (int m = 0; m < 4; m++)
#pragma unroll
        for (int n = 0; n < 4; n++)
          acc[m][n] = __builtin_amdgcn_mfma_f32_16x16x32_bf16(a[m], b[n], acc[m][n], 0, 0, 0);
    }
    __syncthreads();
  }

  const int which = blockIdx.x / 6;
  const int cbase = (blockIdx.x - which * 6) * 128 + wc * 64;
  unsigned short* dst = which == 0 ? q : (which == 1 ? k : v);
#pragma unroll
  for (int m = 0; m < 4; m++) {
    const int grow = m0 + wr * 64 + m * 16 + g * 4;
#pragma unroll
    for (int n = 0; n < 4; n++) {
      const int c = cbase + n * 16 + r;
      const int head = c >> 6, dim = c & 63;
#pragma unroll
      for (int reg = 0; reg < 4; reg++) {
        const int row = grow + reg;
        const int bb = row >> 10, tok = row & 1023;
        dst[((size_t)(((bb * NH + head) << 10) + tok) << 6) + dim] = f2bf(acc[m][n][reg]);
      }
    }
  }
}

// ---------------- K2: flash attention, bf16 MFMA, prefetch + bitmask
__global__ __launch_bounds__(256) void k_attn(const unsigned short* __restrict__ qb,
                                              const unsigned short* __restrict__ kb,
                                              const unsigned short* __restrict__ vb,
                                              const float* __restrict__ dm,
                                              float* __restrict__ out0) {
  __shared__ __align__(16) unsigned short QsA[4096];
  __shared__ __align__(16) unsigned short KsA[2][4096];
  __shared__ __align__(16) unsigned short VtA[2][4096];
  __shared__ __align__(16) unsigned short PsA[4096];
  __shared__ __align__(8) unsigned short MbA[2][64][4];
  char* qs = (char*)QsA;
  char* ps = (char*)PsA;
  const int bh = blockIdx.x;
  const int qt = blockIdx.y;
  const int t  = threadIdx.x;
  const int w = t >> 6, l = t & 63, r = l & 15, g = l >> 4;
  const size_t hbase = (size_t)bh << 16;
  const char* qg = (const char*)(qb + hbase + ((size_t)qt << 12));
  const char* kg = (const char*)(kb + hbase);
  const char* vg = (const char*)(vb + hbase);
  const float* mp = dm + ((size_t)bh << 20) + ((size_t)(qt * 64) << 10);

  const int mrow = t >> 2, mq = t & 3;            // mask staging coords
  const float* mrow_p = mp + (size_t)mrow * 1024 + mq * 16;
  const int rsel = l >> 3;
  const int kslotp = (l & 7) ^ (rsel & 7);

  // ---- prologue: stage Q (reg->swizzled LDS)
#pragma unroll
  for (int i = 0; i < 2; i++) {
    int cid = t + (i << 8);
    int row = cid >> 3, slot = cid & 7;
    uint4 val = *(const uint4*)(qg + row * 128 + slot * 16);
    *(uint4*)(qs + SWZ(row, slot * 16)) = val;
  }
  // K0 via gload_lds
#pragma unroll
  for (int i = 0; i < 2; i++) {
    const int chunk = (i << 2) + w;
    const int row = (chunk << 3) + rsel;
    GLOAD16(kg + (size_t)row * 128 + kslotp * 16,
            (char*)KsA[0] + (chunk << 10) + (l << 4));
  }
  // V0 + mask0 to regs, then write
  {
    u16x8 v0 = *(const u16x8*)(vg + (size_t)l * 128 + w * 32);
    u16x8 v1 = *(const u16x8*)(vg + (size_t)l * 128 + w * 32 + 16);
    float4 nm0 = *(const float4*)(mrow_p);
    float4 nm1 = *(const float4*)(mrow_p + 4);
    float4 nm2 = *(const float4*)(mrow_p + 8);
    float4 nm3 = *(const float4*)(mrow_p + 12);
    char* vt0 = (char*)VtA[0];
#pragma unroll
    for (int e = 0; e < 8; e++) {
      *(unsigned short*)(vt0 + SWZ(w * 16 + e, 2 * l))     = v0[e];
      *(unsigned short*)(vt0 + SWZ(w * 16 + 8 + e, 2 * l)) = v1[e];
    }
    unsigned bits = 0;
    bits |= (nm0.x < 0.1f) << 0;  bits |= (nm0.y < 0.1f) << 1;
    bits |= (nm0.z < 0.1f) << 2;  bits |= (nm0.w < 0.1f) << 3;
    bits |= (nm1.x < 0.1f) << 4;  bits |= (nm1.y < 0.1f) << 5;
    bits |= (nm1.z < 0.1f) << 6;  bits |= (nm1.w < 0.1f) << 7;
    bits |= (nm2.x < 0.1f) << 8;  bits |= (nm2.y < 0.1f) << 9;
    bits |= (nm2.z < 0.1f) << 10; bits |= (nm2.w < 0.1f) << 11;
    bits |= (nm3.x < 0.1f) << 12; bits |= (nm3.y < 0.1f) << 13;
    bits |= (nm3.z < 0.1f) << 14; bits |= (nm3.w < 0.1f) << 15;
    MbA[0][mrow][mq] = (unsigned short)bits;
  }
  __syncthreads();

  // Q fragments fixed for the whole kernel
  bf16x8 aQ[2];
#pragma unroll
  for (int kc = 0; kc < 2; kc++)
    aQ[kc] = *(const bf16x8*)(qs + SWZ(w * 16 + r, kc * 64 + g * 16));

  float m_run[4] = {-INFINITY, -INFINITY, -INFINITY, -INFINITY};
  float l_run[4] = {0.0f, 0.0f, 0.0f, 0.0f};
  f32x4 O[4] = {};

  for (int kt = 0; kt < 16; kt++) {
    const int cur = kt & 1, nxt = cur ^ 1;
    u16x8 nv0, nv1;
    float4 nm0, nm1, nm2, nm3;
    if (kt < 15) {          // issue next tile's loads early (T14)
      const size_t roff = (size_t)((kt + 1) * 64);
#pragma unroll
      for (int i = 0; i < 2; i++) {
        const int chunk = (i << 2) + w;
        const int row = (chunk << 3) + rsel;
        GLOAD16(kg + (roff + row) * 128 + kslotp * 16,
                (char*)KsA[nxt] + (chunk << 10) + (l << 4));
      }
      nv0 = *(const u16x8*)(vg + (roff + l) * 128 + w * 32);
      nv1 = *(const u16x8*)(vg + (roff + l) * 128 + w * 32 + 16);
      const float* mrp = mrow_p + (kt + 1) * 64;
      nm0 = *(const float4*)(mrp);
      nm1 = *(const float4*)(mrp + 4);
      nm2 = *(const float4*)(mrp + 8);
      nm3 = *(const float4*)(mrp + 12);
    }
    // mask bits for current tile (broadcast ds_read_b64 per row)
    unsigned short mbq[4][4];
#pragma unroll
    for (int reg = 0; reg < 4; reg++) {
      ushort4 m4 = *(const ushort4*)&MbA[cur][w * 16 + g * 4 + reg][0];
      mbq[reg][0] = m4.x; mbq[reg][1] = m4.y; mbq[reg][2] = m4.z; mbq[reg][3] = m4.w;
    }

    // ---- QK^T
    f32x4 s[4] = {};
    char* ksc = (char*)KsA[cur];
#pragma unroll
    for (int jt = 0; jt < 4; jt++) {
#pragma unroll
      for (int kc = 0; kc < 2; kc++) {
        bf16x8 bK = *(const bf16x8*)(ksc + SWZ(jt * 16 + r, kc * 64 + g * 16));
        s[jt] = __builtin_amdgcn_mfma_f32_16x16x32_bf16(aQ[kc], bK, s[jt], 0, 0, 0);
      }
    }
    float sv[4][4];
#pragma unroll
    for (int jt = 0; jt < 4; jt++)
#pragma unroll
      for (int reg = 0; reg < 4; reg++) {
        const float pen = ((mbq[reg][jt] >> r) & 1) ? -1e12f : 0.0f;
        sv[jt][reg] = fmaf(s[jt][reg], 0.125f, pen);
      }

    // ---- online softmax (16-lane row groups)
    float alpha[4];
#pragma unroll
    for (int reg = 0; reg < 4; reg++) {
      float mt = fmaxf(fmaxf(sv[0][reg], sv[1][reg]), fmaxf(sv[2][reg], sv[3][reg]));
      mt = fmaxf(mt, __shfl_xor(mt, 1));
      mt = fmaxf(mt, __shfl_xor(mt, 2));
      mt = fmaxf(mt, __shfl_xor(mt, 4));
      mt = fmaxf(mt, __shfl_xor(mt, 8));
      float mn = fmaxf(m_run[reg], mt);
      alpha[reg] = __expf(m_run[reg] - mn);
      m_run[reg] = mn;
    }
#pragma unroll
    for (int reg = 0; reg < 4; reg++) {
      int row = w * 16 + g * 4 + reg;
      float ps_ = 0.0f;
#pragma unroll
      for (int jt = 0; jt < 4; jt++) {
        float p = __expf(sv[jt][reg] - m_run[reg]);
        ps_ += p;
        *(unsigned short*)(ps + SWZ(row, 2 * (jt * 16 + r))) = f2bf(p);
      }
      ps_ += __shfl_xor(ps_, 1);
      ps_ += __shfl_xor(ps_, 2);
      ps_ += __shfl_xor(ps_, 4);
      ps_ += __shfl_xor(ps_, 8);
      l_run[reg] = l_run[reg] * alpha[reg] + ps_;
    }
#pragma unroll
    for (int dt = 0; dt < 4; dt++)
#pragma unroll
      for (int reg = 0; reg < 4; reg++)
        O[dt][reg] *= alpha[reg];
    // P writes are same-wave-read only: drain DS, fence scheduler (rule 18)
    asm volatile("s_waitcnt lgkmcnt(0)" ::: "memory");
    __builtin_amdgcn_sched_barrier(0);
    // ---- PV
    char* vtc = (char*)VtA[cur];
#pragma unroll
    for (int kc = 0; kc < 2; kc++) {
      bf16x8 aP = *(const bf16x8*)(ps + SWZ(w * 16 + r, kc * 64 + g * 16));
#pragma unroll
      for (int dt = 0; dt < 4; dt++) {
        bf16x8 bV = *(const bf16x8*)(vtc + SWZ(dt * 16 + r, kc * 64 + g * 16));
        O[dt] = __builtin_amdgcn_mfma_f32_16x16x32_bf16(aP, bV, O[dt], 0, 0, 0);
      }
    }
    // ---- write-late: stage next V + mask bits
    if (kt < 15) {
      char* vtn = (char*)VtA[nxt];
#pragma unroll
      for (int e = 0; e < 8; e++) {
        *(unsigned short*)(vtn + SWZ(w * 16 + e, 2 * l))     = nv0[e];
        *(unsigned short*)(vtn + SWZ(w * 16 + 8 + e, 2 * l)) = nv1[e];
      }
      unsigned bits = 0;
      bits |= (nm0.x < 0.1f) << 0;  bits |= (nm0.y < 0.1f) << 1;
      bits |= (nm0.z < 0.1f) << 2;  bits |= (nm0.w < 0.1f) << 3;
      bits |= (nm1.x < 0.1f) << 4;  bits |= (nm1.y < 0.1f) << 5;
      bits |= (nm1.z < 0.1f) << 6;  bits |= (nm1.w < 0.1f) << 7;
      bits |= (nm2.x < 0.1f) << 8;  bits |= (nm2.y < 0.1f) << 9;
      bits |= (nm2.z < 0.1f) << 10; bits |= (nm2.w < 0.1f) << 11;
      bits |= (nm3.x < 0.1f) << 12; bits |= (nm3.y < 0.1f) << 13;
      bits |= (nm3.z < 0.1f) << 14; bits |= (nm3.w < 0.1f) << 15;
      MbA[nxt][mrow][mq] = (unsigned short)bits;
    }
    __syncthreads();
  }

  const int bb = bh / NH, hh = bh % NH;
  float inv[4];
#pragma unroll
  for (int reg = 0; reg < 4; reg++) inv[reg] = 1.0f / l_run[reg];
  float* op = out0 + ((size_t)(bb * 1024 + qt * 64 + w * 16 + g * 4)) * 768 + hh * 64 + r;
#pragma unroll
  for (int reg = 0; reg < 4; reg++)
#pragma unroll
    for (int dt = 0; dt < 4; dt++)
      op[(size_t)reg * 768 + dt * 16] = O[dt][reg] * inv[reg];
}

// ---------------- K3: depthwise 3x3 'SAME'
__global__ __launch_bounds__(256) void k_dwconv(const float* __restrict__ y,
                                                const float* __restrict__ w1,
                                                float* __restrict__ y1) {
  const int bc = blockIdx.x;
  const int c = bc & 255;
  const float* yin = y + (size_t)bc * NPIX;
  float* yout = y1 + (size_t)bc * NPIX;
  float w[9];
#pragma unroll
  for (int i = 0; i < 9; i++) w[i] = w1[c * 9 + i];
  const int t = threadIdx.x;
#pragma unroll
  for (int rep = 0; rep < 4; rep++) {
    int px = t + rep * 256;
    int yy = px >> 5, xx = px & 31;
    float acc = 0.0f;
#pragma unroll
    for (int dy = -1; dy <= 1; dy++) {
      int sy = yy + dy;
      if (sy < 0 || sy > 31) continue;
#pragma unroll
      for (int dx = -1; dx <= 1; dx++) {
        int sx = xx + dx;
        if (sx < 0 || sx > 31) continue;
        acc = fmaf(yin[(sy << 5) + sx], w[(dy + 1) * 3 + dx + 1], acc);
      }
    }
    yout[px] = acc;
  }
}

// ---------------- K3b: y1 [b][c][p] f32 -> y1t [b][p][c] bf16
__global__ __launch_bounds__(256) void k_trans(const float* __restrict__ y1,
                                               unsigned short* __restrict__ y1t) {
  __shared__ float T[64][65];
  const int p0 = blockIdx.x * 64, c0 = blockIdx.y * 64, b = blockIdx.z;
  const int t = threadIdx.x;
  const float* src = y1 + ((size_t)b << 18);
  {
    const int pl = t & 63, cl0 = t >> 6;
#pragma unroll
    for (int i = 0; i < 16; i++) {
      int cl = cl0 * 16 + i;
      T[cl][pl] = src[(size_t)(c0 + cl) * 1024 + p0 + pl];
    }
  }
  __syncthreads();
  {
    const int cl = t & 63, pl0 = t >> 6;
    unsigned short* dst = y1t + ((size_t)b << 18);
#pragma unroll
    for (int i = 0; i < 16; i++) {
      int pl = pl0 * 16 + i;
      dst[(size_t)(p0 + pl) * 256 + c0 + cl] = f2bf(T[cl][pl]);
    }
  }
}

// ---------------- K4: 1x1 conv bf16 MFMA, 2-phase prefetch; fused BN partials
__global__ __launch_bounds__(256) void k_c1x1(const unsigned short* __restrict__ W2b,
                                              const unsigned short* __restrict__ y1t,
                                              float* __restrict__ Y2,
                                              float* __restrict__ bn_sum,
                                              float* __restrict__ bn_sumsq) {
  __shared__ __align__(16) char AsB[2][16384];
  __shared__ __align__(16) char BsB[2][16384];
  const int t = threadIdx.x;
  const int w = t >> 6, l = t & 63;
  const int r = l & 15, g = l >> 4;
  const int wr = w >> 1, wc = w & 1;
  const int m0 = blockIdx.y * 128;
  const int n0 = blockIdx.x * 128;
  const int b  = blockIdx.z;
  const unsigned short* A0 = W2b + (size_t)m0 * 256;
  const unsigned short* B0 = y1t + ((size_t)b << 18) + (size_t)n0 * 256;
  const int rsel  = l >> 3;
  const int slotp = (l & 7) ^ (rsel & 7);
  f32x4 acc[4][4] = {};

  stage_pair(A0, 256, B0, 256, AsB[0], BsB[0], w, l, rsel, slotp);
  __syncthreads();

  for (int step = 0; step < 4; ++step) {
    const int cur = step & 1;
    if (step < 3)
      stage_pair(A0 + (step + 1) * 64, 256, B0 + (step + 1) * 64, 256,
                 AsB[cur ^ 1], BsB[cur ^ 1], w, l, rsel, slotp);
#pragma unroll
    for (int kk = 0; kk < 2; kk++) {
      bf16x8 a[4], bfr[4];
#pragma unroll
      for (int m = 0; m < 4; m++) {
        const int row = wr * 64 + m * 16 + r;
        a[m] = *(const bf16x8*)(AsB[cur] + SWZ(row, kk * 64 + (g << 4)));
      }
#pragma unroll
      for (int n = 0; n < 4; n++) {
        const int row = wc * 64 + n * 16 + r;
        bfr[n] = *(const bf16x8*)(BsB[cur] + SWZ(row, kk * 64 + (g << 4)));
      }
#pragma unroll
      for (int m = 0; m < 4; m++)
#pragma unroll
        for (int n = 0; n < 4; n++)
          acc[m][n] = __builtin_amdgcn_mfma_f32_16x16x32_bf16(a[m], bfr[n], acc[m][n], 0, 0, 0);
    }
    __syncthreads();
  }

  float* Yb = Y2 + (((size_t)b * DMODEL) << 10);
#pragma unroll
  for (int m = 0; m < 4; m++) {
#pragma unroll
    for (int reg = 0; reg < 4; reg++) {
      const int oc = m0 + wr * 64 + m * 16 + g * 4 + reg;
      float s = 0.0f, sq = 0.0f;
#pragma unroll
      for (int n = 0; n < 4; n++) {
        const int p = n0 + wc * 64 + n * 16 + r;
        const float val = acc[m][n][reg];
        Yb[((size_t)oc << 10) + p] = val;
        s += val;
        sq = fmaf(val, val, sq);
      }
      s  += __shfl_xor(s, 1);  sq += __shfl_xor(sq, 1);
      s  += __shfl_xor(s, 2);  sq += __shfl_xor(sq, 2);
      s  += __shfl_xor(s, 4);  sq += __shfl_xor(sq, 4);
      s  += __shfl_xor(s, 8);  sq += __shfl_xor(sq, 8);
      if (r == 0) {
        atomicAdd(&bn_sum[oc], s);
        atomicAdd(&bn_sumsq[oc], sq);
      }
    }
  }
}

// ---------------- K6: scale/shift from sums, BN+ReLU -> out1, transpose-add into out0
__global__ __launch_bounds__(256) void k_bnfuse(const float* __restrict__ y2,
                                                const float* __restrict__ bn_sum,
                                                const float* __restrict__ bn_sumsq,
                                                const float* __restrict__ gamma,
                                                const float* __restrict__ beta,
                                                float* __restrict__ out0,
                                                float* __restrict__ out1) {
  __shared__ float T[32][33];
  __shared__ float sc_l[32], sh_l[32];
  const int p0 = blockIdx.x * 32;
  const int c0 = blockIdx.y * 32;
  const int bb = blockIdx.z;
  const int tx = threadIdx.x;
  const int ty = threadIdx.y;
  const int tt = ty * 32 + tx;
  if (tt < 32) {
    const int c = c0 + tt;
    float S = bn_sum[c], SQ = bn_sumsq[c];
    float mean = S * (1.0f / 4096.0f);
    float var = SQ * (1.0f / 4096.0f) - mean * mean;
    float rstd = rsqrtf(var + 1e-5f);
    float s = gamma[c] * rstd;
    sc_l[tt] = s;
    sh_l[tt] = fmaf(-mean, s, beta[c]);
  }
  __syncthreads();
#pragma unroll
  for (int i = 0; i < 4; i++) {
    int cl = ty + 8 * i;
    int c = c0 + cl;
    size_t a = ((size_t)(bb * DMODEL + c) << 10) + p0 + tx;
    float val = fmaxf(fmaf(y2[a], sc_l[cl], sh_l[cl]), 0.0f);
    out1[a] = val;
    T[cl][tx] = val;
  }
  __syncthreads();
#pragma unroll
  for (int i = 0; i < 4; i++) {
    int pl = ty + 8 * i;
    size_t a = ((size_t)((bb << 10) + p0 + pl)) * DMODEL + c0 + tx;
    out0[a] += T[tx][pl];
  }
}

extern "C" void kernel_launch(void* const* d_in, const int* in_sizes, int n_in,
                              void* d_out, int out_size, void* d_ws, size_t ws_size,
                              hipStream_t stream) {
  (void)in_sizes; (void)n_in; (void)out_size; (void)ws_size;
  const float* x    = (const float*)d_in[0];
  const float* y    = (const float*)d_in[1];
  const float* dm   = (const float*)d_in[2];
  const float* wqkv = (const float*)d_in[3];
  const float* w1   = (const float*)d_in[4];
  const float* w2   = (const float*)d_in[5];
  const float* gam  = (const float*)d_in[6];
  const float* bet  = (const float*)d_in[7];
  float* out0 = (float*)d_out;
  float* out1 = out0 + (size_t)B_ * NTOK * DMODEL;

  char* wsb = (char*)d_ws;
  unsigned short* Xb  = (unsigned short*)wsb;
  unsigned short* Wtb = (unsigned short*)(wsb + 6291456);
  unsigned short* W2b = (unsigned short*)(wsb + 9830400);
  unsigned short* qb  = (unsigned short*)(wsb + 10223616);
  unsigned short* kb  = (unsigned short*)(wsb + 16515072);
  unsigned short* vb  = (unsigned short*)(wsb + 22806528);
  unsigned short* y1t = (unsigned short*)(wsb + 29097984);
  float* y2 = (float*)(wsb + 31195136);
  float* y1 = (float*)(wsb + 35389440);
  float* bnacc = (float*)(wsb + 43778048);
  float* bn_sum = bnacc;
  float* bn_sumsq = bnacc + 768;

  k_cvt<<<dim3(3361), 256, 0, stream>>>(x, wqkv, w2, Xb, Wtb, W2b, bnacc);
  k_dwconv<<<dim3(B_ * IMGC), 256, 0, stream>>>(y, w1, y1);
  k_trans<<<dim3(16, 4, B_), 256, 0, stream>>>(y1, y1t);
  k_c1x1<<<dim3(8, 6, B_), 256, 0, stream>>>(W2b, y1t, y2, bn_sum, bn_sumsq);
  k_qkv_gemm<<<dim3(18, 32), 256, 0, stream>>>(Xb, Wtb, qb, kb, vb);
  k_attn<<<dim3(48, 16), 256, 0, stream>>>(qb, kb, vb, dm, out0);
  k_bnfuse<<<dim3(32, 24, B_), dim3(32, 8), 0, stream>>>(y2, bn_sum, bn_sumsq, gam, bet, out0, out1);
}

// Round 7
// 133.657 us; speedup vs baseline: 1.0602x; 1.0602x over previous
//
#include <hip/hip_runtime.h>
#include <cstddef>

#define B_     4
#define NTOK   1024
#define DMODEL 768
#define NH     12
#define IMGC   256
#define NPIX   1024

typedef __attribute__((ext_vector_type(8))) short bf16x8;
typedef __attribute__((ext_vector_type(4))) float f32x4;
typedef __attribute__((ext_vector_type(8))) unsigned short u16x8;

static __device__ __forceinline__ unsigned short f2bf(float f) {
  unsigned int u = __float_as_uint(f);
  u += 0x7FFFu + ((u >> 16) & 1u);
  return (unsigned short)(u >> 16);
}

// swizzled LDS byte address: 128B rows, XOR bits 4..6 with row&7
#define SWZ(row, b) (((row) << 7) + ((b) ^ (((row) & 7) << 4)))

#define GLOAD16(g, l) __builtin_amdgcn_global_load_lds(                      \
    (const __attribute__((address_space(1))) void*)(g),                      \
    (__attribute__((address_space(3))) void*)(l), 16, 0, 0)

// ---------------- K0: merged converts + BN-accumulator zeroing
__global__ __launch_bounds__(256) void k_cvt(const float* __restrict__ X,
                                             const float* __restrict__ Wqkv,
                                             const float* __restrict__ W2,
                                             unsigned short* __restrict__ Xb,
                                             unsigned short* __restrict__ Wtb,
                                             unsigned short* __restrict__ W2b,
                                             float* __restrict__ bnacc) {
  __shared__ unsigned short T[32][33];
  const int bid = blockIdx.x;
  const int t = threadIdx.x;
  if (bid < 1536) {
    const size_t i8 = (size_t)bid * 256 + t;
    const float4 a = *(const float4*)(X + i8 * 8);
    const float4 b = *(const float4*)(X + i8 * 8 + 4);
    u16x8 o;
    o[0] = f2bf(a.x); o[1] = f2bf(a.y); o[2] = f2bf(a.z); o[3] = f2bf(a.w);
    o[4] = f2bf(b.x); o[5] = f2bf(b.y); o[6] = f2bf(b.z); o[7] = f2bf(b.w);
    *(u16x8*)(Xb + i8 * 8) = o;
  } else if (bid < 3264) {
    const int b2 = bid - 1536;
    const int n0 = (b2 % 72) * 32, k0 = (b2 / 72) * 32;
    const int tx = t & 31, ty = t >> 5;
#pragma unroll
    for (int i = 0; i < 4; i++) {
      int kl = ty + i * 8;
      T[tx][kl] = f2bf(Wqkv[(size_t)(k0 + kl) * 2304 + n0 + tx]);
    }
    __syncthreads();
#pragma unroll
    for (int i = 0; i < 4; i++) {
      int nl = ty + i * 8;
      Wtb[(size_t)(n0 + nl) * 768 + k0 + tx] = T[nl][tx];
    }
  } else if (bid < 3360) {
    const size_t i8 = (size_t)(bid - 3264) * 256 + t;
    const float4 a = *(const float4*)(W2 + i8 * 8);
    const float4 b = *(const float4*)(W2 + i8 * 8 + 4);
    u16x8 o;
    o[0] = f2bf(a.x); o[1] = f2bf(a.y); o[2] = f2bf(a.z); o[3] = f2bf(a.w);
    o[4] = f2bf(b.x); o[5] = f2bf(b.y); o[6] = f2bf(b.z); o[7] = f2bf(b.w);
    *(u16x8*)(W2b + i8 * 8) = o;
  } else {
    for (int i = t; i < 1536; i += 256) bnacc[i] = 0.0f;
  }
}

// ---------------- K1: QKV GEMM bf16 MFMA (single-buffer, round-4 structure)
__global__ __launch_bounds__(256) void k_qkv_gemm(const unsigned short* __restrict__ Xb,
                                                  const unsigned short* __restrict__ Wt,
                                                  unsigned short* __restrict__ q,
                                                  unsigned short* __restrict__ k,
                                                  unsigned short* __restrict__ v) {
  __shared__ __align__(16) char AsB[16384];
  __shared__ __align__(16) char BsB[16384];
  const int t = threadIdx.x;
  const int w = t >> 6, l = t & 63;
  const int r = l & 15, g = l >> 4;
  const int wr = w >> 1, wc = w & 1;
  const int m0 = blockIdx.y * 128;
  const int n0 = blockIdx.x * 128;
  const int rsel  = l >> 3;
  const int slotp = (l & 7) ^ (rsel & 7);
  f32x4 acc[4][4] = {};

  for (int step = 0; step < 12; ++step) {
    const int k0 = step * 64;
#pragma unroll
    for (int i = 0; i < 4; i++) {
      const int chunk = (i << 2) + w;
      const int row = (chunk << 3) + rsel;
      GLOAD16(Xb + (size_t)(m0 + row) * 768 + k0 + (slotp << 3),
              AsB + (chunk << 10) + (l << 4));
      GLOAD16(Wt + (size_t)(n0 + row) * 768 + k0 + (slotp << 3),
              BsB + (chunk << 10) + (l << 4));
    }
    __syncthreads();
#pragma unroll
    for (int kk = 0; kk < 2; kk++) {
      bf16x8 a[4], b[4];
#pragma unroll
      for (int m = 0; m < 4; m++) {
        const int row = wr * 64 + m * 16 + r;
        a[m] = *(const bf16x8*)(AsB + SWZ(row, kk * 64 + (g << 4)));
      }
#pragma unroll
      for (int n = 0; n < 4; n++) {
        const int row = wc * 64 + n * 16 + r;
        b[n] = *(const bf16x8*)(BsB + SWZ(row, kk * 64 + (g << 4)));
      }
#pragma unroll
      for (int m = 0; m < 4; m++)
#pragma unroll
        for (int n = 0; n < 4; n++)
          acc[m][n] = __builtin_amdgcn_mfma_f32_16x16x32_bf16(a[m], b[n], acc[m][n], 0, 0, 0);
    }
    __syncthreads();
  }

  const int which = blockIdx.x / 6;
  const int cbase = (blockIdx.x - which * 6) * 128 + wc * 64;
  unsigned short* dst = which == 0 ? q : (which == 1 ? k : v);
#pragma unroll
  for (int m = 0; m < 4; m++) {
    const int grow = m0 + wr * 64 + m * 16 + g * 4;
#pragma unroll
    for (int n = 0; n < 4; n++) {
      const int c = cbase + n * 16 + r;
      const int head = c >> 6, dim = c & 63;
#pragma unroll
      for (int reg = 0; reg < 4; reg++) {
        const int row = grow + reg;
        const int bb = row >> 10, tok = row & 1023;
        dst[((size_t)(((bb * NH + head) << 10) + tok) << 6) + dim] = f2bf(acc[m][n][reg]);
      }
    }
  }
}

// ---------------- K2: flash attention. LDS-neutral pipeline:
// Q read to regs once; its LDS reused as K buffer 1. K prefetched via
// global_load_lds; V issue-early/write-late (T14).
__global__ __launch_bounds__(256) void k_attn(const unsigned short* __restrict__ qb,
                                              const unsigned short* __restrict__ kb,
                                              const unsigned short* __restrict__ vb,
                                              const float* __restrict__ dm,
                                              float* __restrict__ out0) {
  __shared__ __align__(16) unsigned short K0A[4096];   // K buffer 0
  __shared__ __align__(16) unsigned short K1A[4096];   // Q staging, then K buffer 1
  __shared__ __align__(16) unsigned short VtA[4096];   // V transposed [d][j]
  __shared__ __align__(16) unsigned short PsA[4096];
  char* ps = (char*)PsA;
  char* vt = (char*)VtA;
  const int bh = blockIdx.x;
  const int qt = blockIdx.y;
  const int t  = threadIdx.x;
  const int w = t >> 6, l = t & 63, r = l & 15, g = l >> 4;
  const size_t hbase = (size_t)bh << 16;
  const char* qg = (const char*)(qb + hbase + ((size_t)qt << 12));
  const char* kg = (const char*)(kb + hbase);
  const char* vg = (const char*)(vb + hbase);
  const float* mp = dm + ((size_t)bh << 20) + ((size_t)(qt * 64) << 10);

  const int rsel = l >> 3;
  const int kslotp = (l & 7) ^ (rsel & 7);
  const float* mr_base = mp + (size_t)(w * 16 + g * 4) * 1024 + r;

  // ---- prologue: Q -> K1A (temp), K0 -> K0A via gload_lds, V0 -> VtA
  {
    char* qs = (char*)K1A;
#pragma unroll
    for (int i = 0; i < 2; i++) {
      int cid = t + (i << 8);
      int row = cid >> 3, slot = cid & 7;
      uint4 val = *(const uint4*)(qg + row * 128 + slot * 16);
      *(uint4*)(qs + SWZ(row, slot * 16)) = val;
    }
  }
#pragma unroll
  for (int i = 0; i < 2; i++) {
    const int chunk = (i << 2) + w;
    const int row = (chunk << 3) + rsel;
    GLOAD16(kg + (size_t)row * 128 + kslotp * 16,
            (char*)K0A + (chunk << 10) + (l << 4));
  }
  {
    u16x8 v0 = *(const u16x8*)(vg + (size_t)l * 128 + w * 32);
    u16x8 v1 = *(const u16x8*)(vg + (size_t)l * 128 + w * 32 + 16);
#pragma unroll
    for (int e = 0; e < 8; e++) {
      *(unsigned short*)(vt + SWZ(w * 16 + e, 2 * l))     = v0[e];
      *(unsigned short*)(vt + SWZ(w * 16 + 8 + e, 2 * l)) = v1[e];
    }
  }
  __syncthreads();          // Q, K0, V0 all visible

  // Q fragments to registers; then K1A becomes K buffer 1
  bf16x8 aQ[2];
#pragma unroll
  for (int kc = 0; kc < 2; kc++)
    aQ[kc] = *(const bf16x8*)((char*)K1A + SWZ(w * 16 + r, kc * 64 + g * 16));
  asm volatile("s_waitcnt lgkmcnt(0)" ::: "memory");
  __builtin_amdgcn_sched_barrier(0);
  __syncthreads();          // all waves hold aQ before K1A is overwritten

  float m_run[4] = {-INFINITY, -INFINITY, -INFINITY, -INFINITY};
  float l_run[4] = {0.0f, 0.0f, 0.0f, 0.0f};
  f32x4 O[4] = {};

  for (int kt = 0; kt < 16; kt++) {
    const int cur = kt & 1;
    char* ksc = cur ? (char*)K1A : (char*)K0A;
    char* ksn = cur ? (char*)K0A : (char*)K1A;
    // ---- issue-early: next K via gload_lds, next V to regs (T14)
    u16x8 nv0, nv1;
    if (kt < 15) {
      const size_t roff = (size_t)((kt + 1) * 64);
#pragma unroll
      for (int i = 0; i < 2; i++) {
        const int chunk = (i << 2) + w;
        const int row = (chunk << 3) + rsel;
        GLOAD16(kg + (roff + row) * 128 + kslotp * 16,
                ksn + (chunk << 10) + (l << 4));
      }
      nv0 = *(const u16x8*)(vg + (roff + l) * 128 + w * 32);
      nv1 = *(const u16x8*)(vg + (roff + l) * 128 + w * 32 + 16);
    }
    // mask for current tile
    float md[4][4];
    {
      const float* mr = mr_base + kt * 64;
#pragma unroll
      for (int reg = 0; reg < 4; reg++)
#pragma unroll
        for (int jt = 0; jt < 4; jt++)
          md[reg][jt] = mr[reg * 1024 + jt * 16];
    }

    // ---- QK^T
    f32x4 s[4] = {};
#pragma unroll
    for (int jt = 0; jt < 4; jt++) {
#pragma unroll
      for (int kc = 0; kc < 2; kc++) {
        bf16x8 bK = *(const bf16x8*)(ksc + SWZ(jt * 16 + r, kc * 64 + g * 16));
        s[jt] = __builtin_amdgcn_mfma_f32_16x16x32_bf16(aQ[kc], bK, s[jt], 0, 0, 0);
      }
    }
    float sv[4][4];
#pragma unroll
    for (int jt = 0; jt < 4; jt++)
#pragma unroll
      for (int reg = 0; reg < 4; reg++)
        sv[jt][reg] = s[jt][reg] * 0.125f + (md[reg][jt] < 0.1f ? -1e12f : 0.0f);

    // ---- online softmax (16-lane row groups)
    float alpha[4];
#pragma unroll
    for (int reg = 0; reg < 4; reg++) {
      float mt = fmaxf(fmaxf(sv[0][reg], sv[1][reg]), fmaxf(sv[2][reg], sv[3][reg]));
      mt = fmaxf(mt, __shfl_xor(mt, 1));
      mt = fmaxf(mt, __shfl_xor(mt, 2));
      mt = fmaxf(mt, __shfl_xor(mt, 4));
      mt = fmaxf(mt, __shfl_xor(mt, 8));
      float mn = fmaxf(m_run[reg], mt);
      alpha[reg] = __expf(m_run[reg] - mn);
      m_run[reg] = mn;
    }
#pragma unroll
    for (int reg = 0; reg < 4; reg++) {
      int row = w * 16 + g * 4 + reg;
      float ps_ = 0.0f;
#pragma unroll
      for (int jt = 0; jt < 4; jt++) {
        float p = __expf(sv[jt][reg] - m_run[reg]);
        ps_ += p;
        *(unsigned short*)(ps + SWZ(row, 2 * (jt * 16 + r))) = f2bf(p);
      }
      ps_ += __shfl_xor(ps_, 1);
      ps_ += __shfl_xor(ps_, 2);
      ps_ += __shfl_xor(ps_, 4);
      ps_ += __shfl_xor(ps_, 8);
      l_run[reg] = l_run[reg] * alpha[reg] + ps_;
    }
#pragma unroll
    for (int dt = 0; dt < 4; dt++)
#pragma unroll
      for (int reg = 0; reg < 4; reg++)
        O[dt][reg] *= alpha[reg];
    // P writes are same-wave-read only: drain DS, fence scheduler (rule 18)
    asm volatile("s_waitcnt lgkmcnt(0)" ::: "memory");
    __builtin_amdgcn_sched_barrier(0);
    // ---- PV
#pragma unroll
    for (int kc = 0; kc < 2; kc++) {
      bf16x8 aP = *(const bf16x8*)(ps + SWZ(w * 16 + r, kc * 64 + g * 16));
#pragma unroll
      for (int dt = 0; dt < 4; dt++) {
        bf16x8 bV = *(const bf16x8*)(vt + SWZ(dt * 16 + r, kc * 64 + g * 16));
        O[dt] = __builtin_amdgcn_mfma_f32_16x16x32_bf16(aP, bV, O[dt], 0, 0, 0);
      }
    }
    __syncthreads();        // PV reads done everywhere; K[kt+1] landed
    // ---- write-late: next V into VtA
    if (kt < 15) {
#pragma unroll
      for (int e = 0; e < 8; e++) {
        *(unsigned short*)(vt + SWZ(w * 16 + e, 2 * l))     = nv0[e];
        *(unsigned short*)(vt + SWZ(w * 16 + 8 + e, 2 * l)) = nv1[e];
      }
      __syncthreads();      // next V visible
    }
  }

  const int bb = bh / NH, hh = bh % NH;
  float inv[4];
#pragma unroll
  for (int reg = 0; reg < 4; reg++) inv[reg] = 1.0f / l_run[reg];
  float* op = out0 + ((size_t)(bb * 1024 + qt * 64 + w * 16 + g * 4)) * 768 + hh * 64 + r;
#pragma unroll
  for (int reg = 0; reg < 4; reg++)
#pragma unroll
    for (int dt = 0; dt < 4; dt++)
      op[(size_t)reg * 768 + dt * 16] = O[dt][reg] * inv[reg];
}

// ---------------- K3: depthwise 3x3 'SAME'
__global__ __launch_bounds__(256) void k_dwconv(const float* __restrict__ y,
                                                const float* __restrict__ w1,
                                                float* __restrict__ y1) {
  const int bc = blockIdx.x;
  const int c = bc & 255;
  const float* yin = y + (size_t)bc * NPIX;
  float* yout = y1 + (size_t)bc * NPIX;
  float w[9];
#pragma unroll
  for (int i = 0; i < 9; i++) w[i] = w1[c * 9 + i];
  const int t = threadIdx.x;
#pragma unroll
  for (int rep = 0; rep < 4; rep++) {
    int px = t + rep * 256;
    int yy = px >> 5, xx = px & 31;
    float acc = 0.0f;
#pragma unroll
    for (int dy = -1; dy <= 1; dy++) {
      int sy = yy + dy;
      if (sy < 0 || sy > 31) continue;
#pragma unroll
      for (int dx = -1; dx <= 1; dx++) {
        int sx = xx + dx;
        if (sx < 0 || sx > 31) continue;
        acc = fmaf(yin[(sy << 5) + sx], w[(dy + 1) * 3 + dx + 1], acc);
      }
    }
    yout[px] = acc;
  }
}

// ---------------- K3b: y1 [b][c][p] f32 -> y1t [b][p][c] bf16
__global__ __launch_bounds__(256) void k_trans(const float* __restrict__ y1,
                                               unsigned short* __restrict__ y1t) {
  __shared__ float T[64][65];
  const int p0 = blockIdx.x * 64, c0 = blockIdx.y * 64, b = blockIdx.z;
  const int t = threadIdx.x;
  const float* src = y1 + ((size_t)b << 18);
  {
    const int pl = t & 63, cl0 = t >> 6;
#pragma unroll
    for (int i = 0; i < 16; i++) {
      int cl = cl0 * 16 + i;
      T[cl][pl] = src[(size_t)(c0 + cl) * 1024 + p0 + pl];
    }
  }
  __syncthreads();
  {
    const int cl = t & 63, pl0 = t >> 6;
    unsigned short* dst = y1t + ((size_t)b << 18);
#pragma unroll
    for (int i = 0; i < 16; i++) {
      int pl = pl0 * 16 + i;
      dst[(size_t)(p0 + pl) * 256 + c0 + cl] = f2bf(T[cl][pl]);
    }
  }
}

// ---------------- K4: 1x1 conv bf16 MFMA (single-buffer); fused BN partials
__global__ __launch_bounds__(256) void k_c1x1(const unsigned short* __restrict__ W2b,
                                              const unsigned short* __restrict__ y1t,
                                              float* __restrict__ Y2,
                                              float* __restrict__ bn_sum,
                                              float* __restrict__ bn_sumsq) {
  __shared__ __align__(16) char AsB[16384];
  __shared__ __align__(16) char BsB[16384];
  const int t = threadIdx.x;
  const int w = t >> 6, l = t & 63;
  const int r = l & 15, g = l >> 4;
  const int wr = w >> 1, wc = w & 1;
  const int m0 = blockIdx.y * 128;
  const int n0 = blockIdx.x * 128;
  const int b  = blockIdx.z;
  const unsigned short* Bb = y1t + ((size_t)b << 18);
  const int rsel  = l >> 3;
  const int slotp = (l & 7) ^ (rsel & 7);
  f32x4 acc[4][4] = {};

  for (int step = 0; step < 4; ++step) {
    const int k0 = step * 64;
#pragma unroll
    for (int i = 0; i < 4; i++) {
      const int chunk = (i << 2) + w;
      const int row = (chunk << 3) + rsel;
      GLOAD16(W2b + (size_t)(m0 + row) * 256 + k0 + (slotp << 3),
              AsB + (chunk << 10) + (l << 4));
      GLOAD16(Bb + (size_t)(n0 + row) * 256 + k0 + (slotp << 3),
              BsB + (chunk << 10) + (l << 4));
    }
    __syncthreads();
#pragma unroll
    for (int kk = 0; kk < 2; kk++) {
      bf16x8 a[4], bfr[4];
#pragma unroll
      for (int m = 0; m < 4; m++) {
        const int row = wr * 64 + m * 16 + r;
        a[m] = *(const bf16x8*)(AsB + SWZ(row, kk * 64 + (g << 4)));
      }
#pragma unroll
      for (int n = 0; n < 4; n++) {
        const int row = wc * 64 + n * 16 + r;
        bfr[n] = *(const bf16x8*)(BsB + SWZ(row, kk * 64 + (g << 4)));
      }
#pragma unroll
      for (int m = 0; m < 4; m++)
#pragma unroll
        for (int n = 0; n < 4; n++)
          acc[m][n] = __builtin_amdgcn_mfma_f32_16x16x32_bf16(a[m], bfr[n], acc[m][n], 0, 0, 0);
    }
    __syncthreads();
  }

  float* Yb = Y2 + (((size_t)b * DMODEL) << 10);
#pragma unroll
  for (int m = 0; m < 4; m++) {
#pragma unroll
    for (int reg = 0; reg < 4; reg++) {
      const int oc = m0 + wr * 64 + m * 16 + g * 4 + reg;
      float s = 0.0f, sq = 0.0f;
#pragma unroll
      for (int n = 0; n < 4; n++) {
        const int p = n0 + wc * 64 + n * 16 + r;
        const float val = acc[m][n][reg];
        Yb[((size_t)oc << 10) + p] = val;
        s += val;
        sq = fmaf(val, val, sq);
      }
      s  += __shfl_xor(s, 1);  sq += __shfl_xor(sq, 1);
      s  += __shfl_xor(s, 2);  sq += __shfl_xor(sq, 2);
      s  += __shfl_xor(s, 4);  sq += __shfl_xor(sq, 4);
      s  += __shfl_xor(s, 8);  sq += __shfl_xor(sq, 8);
      if (r == 0) {
        atomicAdd(&bn_sum[oc], s);
        atomicAdd(&bn_sumsq[oc], sq);
      }
    }
  }
}

// ---------------- K6: scale/shift from sums, BN+ReLU -> out1, transpose-add into out0
__global__ __launch_bounds__(256) void k_bnfuse(const float* __restrict__ y2,
                                                const float* __restrict__ bn_sum,
                                                const float* __restrict__ bn_sumsq,
                                                const float* __restrict__ gamma,
                                                const float* __restrict__ beta,
                                                float* __restrict__ out0,
                                                float* __restrict__ out1) {
  __shared__ float T[32][33];
  __shared__ float sc_l[32], sh_l[32];
  const int p0 = blockIdx.x * 32;
  const int c0 = blockIdx.y * 32;
  const int bb = blockIdx.z;
  const int tx = threadIdx.x;
  const int ty = threadIdx.y;
  const int tt = ty * 32 + tx;
  if (tt < 32) {
    const int c = c0 + tt;
    float S = bn_sum[c], SQ = bn_sumsq[c];
    float mean = S * (1.0f / 4096.0f);
    float var = SQ * (1.0f / 4096.0f) - mean * mean;
    float rstd = rsqrtf(var + 1e-5f);
    float s = gamma[c] * rstd;
    sc_l[tt] = s;
    sh_l[tt] = fmaf(-mean, s, beta[c]);
  }
  __syncthreads();
#pragma unroll
  for (int i = 0; i < 4; i++) {
    int cl = ty + 8 * i;
    int c = c0 + cl;
    size_t a = ((size_t)(bb * DMODEL + c) << 10) + p0 + tx;
    float val = fmaxf(fmaf(y2[a], sc_l[cl], sh_l[cl]), 0.0f);
    out1[a] = val;
    T[cl][tx] = val;
  }
  __syncthreads();
#pragma unroll
  for (int i = 0; i < 4; i++) {
    int pl = ty + 8 * i;
    size_t a = ((size_t)((bb << 10) + p0 + pl)) * DMODEL + c0 + tx;
    out0[a] += T[tx][pl];
  }
}

extern "C" void kernel_launch(void* const* d_in, const int* in_sizes, int n_in,
                              void* d_out, int out_size, void* d_ws, size_t ws_size,
                              hipStream_t stream) {
  (void)in_sizes; (void)n_in; (void)out_size; (void)ws_size;
  const float* x    = (const float*)d_in[0];
  const float* y    = (const float*)d_in[1];
  const float* dm   = (const float*)d_in[2];
  const float* wqkv = (const float*)d_in[3];
  const float* w1   = (const float*)d_in[4];
  const float* w2   = (const float*)d_in[5];
  const float* gam  = (const float*)d_in[6];
  const float* bet  = (const float*)d_in[7];
  float* out0 = (float*)d_out;
  float* out1 = out0 + (size_t)B_ * NTOK * DMODEL;

  char* wsb = (char*)d_ws;
  unsigned short* Xb  = (unsigned short*)wsb;
  unsigned short* Wtb = (unsigned short*)(wsb + 6291456);
  unsigned short* W2b = (unsigned short*)(wsb + 9830400);
  unsigned short* qb  = (unsigned short*)(wsb + 10223616);
  unsigned short* kb  = (unsigned short*)(wsb + 16515072);
  unsigned short* vb  = (unsigned short*)(wsb + 22806528);
  unsigned short* y1t = (unsigned short*)(wsb + 29097984);
  float* y2 = (float*)(wsb + 31195136);
  float* y1 = (float*)(wsb + 35389440);
  float* bnacc = (float*)(wsb + 43778048);
  float* bn_sum = bnacc;
  float* bn_sumsq = bnacc + 768;

  k_cvt<<<dim3(3361), 256, 0, stream>>>(x, wqkv, w2, Xb, Wtb, W2b, bnacc);
  k_dwconv<<<dim3(B_ * IMGC), 256, 0, stream>>>(y, w1, y1);
  k_trans<<<dim3(16, 4, B_), 256, 0, stream>>>(y1, y1t);
  k_c1x1<<<dim3(8, 6, B_), 256, 0, stream>>>(W2b, y1t, y2, bn_sum, bn_sumsq);
  k_qkv_gemm<<<dim3(18, 32), 256, 0, stream>>>(Xb, Wtb, qb, kb, vb);
  k_attn<<<dim3(48, 16), 256, 0, stream>>>(qb, kb, vb, dm, out0);
  k_bnfuse<<<dim3(32, 24, B_), dim3(32, 8), 0, stream>>>(y2, bn_sum, bn_sumsq, gam, bet, out0, out1);
}